// Round 6
// baseline (314.284 us; speedup 1.0000x reference)
//
#include <hip/hip_runtime.h>

// TimeConcater: new_x[b,p,d] = sum_l [bucket(ts[b,l])==p] * x[b,l,d]
// B=32, L=4096, D=256, P=32 buckets over np.linspace(0,1.001,33) edges.
// Output flat: new_x (32,32,256), then time_steps (32,4096).
//
// R5: R4's streaming scatter, but with unsafeAtomicAdd. Plain fp32 atomicAdd
// compiles to a CAS retry loop (no -munsafe-fp-atomics in harness flags) —
// measured ~208 cyc per LDS "atomic" in R0/R4, 178 us with all pipes idle.
// unsafeAtomicAdd emits native fire-and-forget ds_add_f32 /
// global_atomic_add_f32: no return, no dependency chain.

#define Bk 32
#define Lk 4096
#define Dk 256
#define Pk 32
#define NT 512            // threads/block (8 waves)
#define CHUNK 256         // rows per block
#define RPW (CHUNK / 8)   // rows per wave = 32

__device__ __forceinline__ int bucket_of(float tv) {
    // Emulate np.linspace(0.0, 1.001, 33): edge(i) = float32((double)i * (1.001/32))
    const double step = 1.001 / 32.0;
    int p = (int)(tv * (float)(32.0 / 1.001));
    p = p < 0 ? 0 : (p > 31 ? 31 : p);
    while (p > 0 && tv < (float)((double)p * step)) --p;
    while (p < 31 && tv >= (float)((double)(p + 1) * step)) ++p;
    return p;
}

__global__ __launch_bounds__(NT, 4) void tc_stream(
        const float* __restrict__ x,
        const float* __restrict__ ts,
        float* __restrict__ out,
        float* __restrict__ ts_out) {
    __shared__ float acc[Pk * Dk];   // 32 KB bucket accumulators
    __shared__ int sbuck[CHUNK];     // per-row bucket

    const int c = blockIdx.x;        // chunk 0..15
    const int b = blockIdx.y;        // batch 0..31
    const int t = threadIdx.x;
    const int w = t >> 6;            // wave 0..7
    const int lane = t & 63;
    const int col4 = lane << 2;      // lane's 4 columns
    const int l0 = c * CHUNK;

    // Zero accumulators (8192 floats / 512 threads = 16 each).
#pragma unroll
    for (int k = 0; k < (Pk * Dk) / NT; ++k)
        acc[t + k * NT] = 0.0f;

    // Buckets for this chunk's 256 rows + ts passthrough for this slice.
    if (t < CHUNK) {
        const float tv = ts[(size_t)b * Lk + l0 + t];
        ts_out[(size_t)b * Lk + l0 + t] = tv;
        sbuck[t] = bucket_of(tv);
    }
    __syncthreads();

    // Stream: wave w owns rows [w*RPW, (w+1)*RPW) — contiguous 32 KB per
    // wave, read once, in order. 8-deep unroll => 8 outstanding 1 KB
    // global_load_dwordx4 per wave; scatter is fire-and-forget ds_add_f32.
    const float* xp = x + ((size_t)b * Lk + l0) * Dk;
    const int rbase = w * RPW;
    for (int i0 = 0; i0 < RPW; i0 += 8) {
        float4 v[8];
#pragma unroll
        for (int j = 0; j < 8; ++j)
            v[j] = *(const float4*)(xp + (size_t)(rbase + i0 + j) * Dk + col4);
#pragma unroll
        for (int j = 0; j < 8; ++j) {
            float* a = &acc[sbuck[rbase + i0 + j] * Dk + col4];
            unsafeAtomicAdd(&a[0], v[j].x);   // ds_add_f32, no-return
            unsafeAtomicAdd(&a[1], v[j].y);
            unsafeAtomicAdd(&a[2], v[j].z);
            unsafeAtomicAdd(&a[3], v[j].w);
        }
    }
    __syncthreads();

    // Flush block-local bucket sums into global out (zeroed by memset node).
    float* ob = out + (size_t)b * (Pk * Dk);
#pragma unroll
    for (int k = 0; k < (Pk * Dk) / NT; ++k) {
        const int idx = t + k * NT;
        unsafeAtomicAdd(&ob[idx], acc[idx]);  // global_atomic_add_f32
    }
}

extern "C" void kernel_launch(void* const* d_in, const int* in_sizes, int n_in,
                              void* d_out, int out_size, void* d_ws, size_t ws_size,
                              hipStream_t stream) {
    const float* x  = (const float*)d_in[0];
    const float* ts = (const float*)d_in[1];
    float* out = (float*)d_out;
    float* ts_out = out + (size_t)Bk * Pk * Dk;

    // Zero new_x region (flush atomics accumulate onto it).
    hipMemsetAsync(out, 0, (size_t)Bk * Pk * Dk * sizeof(float), stream);

    dim3 grid(Lk / CHUNK, Bk);   // (16, 32) = 512 blocks
    tc_stream<<<grid, NT, 0, stream>>>(x, ts, out, ts_out);
}

// Round 7
// 205.821 us; speedup vs baseline: 1.5270x; 1.5270x over previous
//
#include <hip/hip_runtime.h>

// TimeConcater: new_x[b,p,d] = sum_l [bucket(ts[b,l])==p] * x[b,l,d]
// B=32, L=4096, D=256, P=32 buckets over np.linspace(0,1.001,33) edges.
// Output flat: new_x (32,32,256), then time_steps (32,4096).
//
// R6: register-accumulator mask-FMA. Measured R0/R4/R5: LDS fp32 atomics run
// at ~209 cyc/wave-inst regardless of flavor/occupancy/ILP -> banned. Here
// each wave streams 64 contiguous rows and keeps ALL 32 bucket sums for its
// 4 columns in VGPRs (32 x float4 = 128 regs), accumulating via
// scalar-masked FMA (sb is wave-uniform). Cross-wave reduce: serialized
// non-atomic LDS; cross-block: native global atomic flush (proven cheap).

#define Bk 32
#define Lk 4096
#define Dk 256
#define Pk 32
#define NT 256            // 4 waves
#define CHUNK 256         // rows per block; 64 rows per wave
#define RPW 64

__device__ __forceinline__ int bucket_of(float tv) {
    // Emulate np.linspace(0.0, 1.001, 33): edge(i) = float32((double)i * (1.001/32))
    const double step = 1.001 / 32.0;
    int p = (int)(tv * (float)(32.0 / 1.001));
    p = p < 0 ? 0 : (p > 31 ? 31 : p);
    while (p > 0 && tv < (float)((double)p * step)) --p;
    while (p < 31 && tv >= (float)((double)(p + 1) * step)) ++p;
    return p;
}

__global__ __launch_bounds__(NT, 2) void tc_reg(
        const float* __restrict__ x,
        const float* __restrict__ ts,
        float* __restrict__ out,
        float* __restrict__ ts_out) {
    __shared__ float accb[Pk * Dk];  // 32 KB block-level bucket sums
    __shared__ int sbuck[CHUNK];

    const int c = blockIdx.x;        // chunk 0..15
    const int b = blockIdx.y;        // batch 0..31
    const int t = threadIdx.x;
    const int w = t >> 6;            // wave 0..3
    const int lane = t & 63;
    const int col4 = lane << 2;
    const int l0 = c * CHUNK;

    // Buckets for this chunk + ts passthrough (NT == CHUNK).
    {
        const float tv = ts[(size_t)b * Lk + l0 + t];
        ts_out[(size_t)b * Lk + l0 + t] = tv;
        sbuck[t] = bucket_of(tv);
    }
    __syncthreads();

    // Wave w streams rows [w*64, w*64+64) — 64 KB contiguous.
    const float* xp = x + ((size_t)b * Lk + l0 + (size_t)w * RPW) * Dk;

    float4 acc[Pk];
#pragma unroll
    for (int p = 0; p < Pk; ++p) acc[p] = make_float4(0.f, 0.f, 0.f, 0.f);

    // 4-deep prefetch ring (static indices via 4x row unroll).
    float4 v[4];
#pragma unroll
    for (int j = 0; j < 4; ++j)
        v[j] = *(const float4*)(xp + (size_t)j * Dk + col4);

    for (int r0 = 0; r0 < RPW; r0 += 4) {
#pragma unroll
        for (int j = 0; j < 4; ++j) {
            const int r = r0 + j;
            const float4 cur = v[j];
            // Prefetch row r+4 (clamped; tail prefetches are never consumed).
            const int rn = (r + 4 < RPW) ? (r + 4) : (RPW - 1);
            v[j] = *(const float4*)(xp + (size_t)rn * Dk + col4);
            const int sb = __builtin_amdgcn_readfirstlane(sbuck[w * RPW + r]);
#pragma unroll
            for (int p = 0; p < Pk; ++p) {
                const float m = (p == sb) ? 1.0f : 0.0f;   // scalar 0/1 mask
                acc[p].x = __builtin_fmaf(m, cur.x, acc[p].x);
                acc[p].y = __builtin_fmaf(m, cur.y, acc[p].y);
                acc[p].z = __builtin_fmaf(m, cur.z, acc[p].z);
                acc[p].w = __builtin_fmaf(m, cur.w, acc[p].w);
            }
        }
    }

    // Cross-wave reduce: serialized wave turns, non-atomic LDS RMW,
    // all-static register indices.
#pragma unroll
    for (int s = 0; s < 4; ++s) {
        if (w == s) {
#pragma unroll
            for (int p = 0; p < Pk; ++p) {
                float* a = &accb[p * Dk + col4];
                if (s == 0) {
                    *(float4*)a = acc[p];
                } else {
                    float4 o = *(const float4*)a;
                    o.x += acc[p].x; o.y += acc[p].y;
                    o.z += acc[p].z; o.w += acc[p].w;
                    *(float4*)a = o;
                }
            }
        }
        __syncthreads();
    }

    // Cross-block flush: native fire-and-forget global f32 atomics
    // (4.2M lane-ops total — measured negligible in R4/R5).
    float* ob = out + (size_t)b * (Pk * Dk);
#pragma unroll
    for (int k = 0; k < (Pk * Dk) / NT; ++k) {
        const int idx = t + k * NT;
        unsafeAtomicAdd(&ob[idx], accb[idx]);
    }
}

extern "C" void kernel_launch(void* const* d_in, const int* in_sizes, int n_in,
                              void* d_out, int out_size, void* d_ws, size_t ws_size,
                              hipStream_t stream) {
    const float* x  = (const float*)d_in[0];
    const float* ts = (const float*)d_in[1];
    float* out = (float*)d_out;
    float* ts_out = out + (size_t)Bk * Pk * Dk;

    // Zero new_x region (flush atomics accumulate onto it).
    hipMemsetAsync(out, 0, (size_t)Bk * Pk * Dk * sizeof(float), stream);

    dim3 grid(Lk / CHUNK, Bk);   // (16, 32) = 512 blocks, 2 per CU
    tc_reg<<<grid, NT, 0, stream>>>(x, ts, out, ts_out);
}